// Round 25
// baseline (87.720 us; speedup 1.0000x reference)
//
#include <hip/hip_runtime.h>

constexpr int BB   = 2;
constexpr int NN   = 50000;
constexpr int EE   = 600000;
constexpr int CDIM = 128;
constexpr int SEGS = BB * NN;   // 100000
constexpr int CAP  = 32;        // max degree = 1 + Poisson(5); P(>=32) ~ 1e-10
constexpr int NUNITS = SEGS * CDIM / 8;            // 1.6M 8-float units
constexpr int CVB  = (NUNITS + 1023) / 1024;       // 1563 cvt blocks (4 units/thr)
constexpr int EBLK = (EE + 255) / 256;             // 2344 edge blocks (1 edge/thr)

typedef __attribute__((ext_vector_type(8))) short bf16x8;
typedef __attribute__((ext_vector_type(4))) float f32x4;

__device__ __forceinline__ unsigned short f2bf(float f) {
    unsigned u = __builtin_bit_cast(unsigned, f);
    return (unsigned short)((u + 0x7FFFu + ((u >> 16) & 1u)) >> 16);  // RNE
}
__device__ __forceinline__ float bf2f(unsigned short v) {
    unsigned u = ((unsigned)v) << 16;
    return __builtin_bit_cast(float, u);
}

// ---------------------------------------------------------------------------
// cvt_k: LAST block (blockIdx == gridDim-1) converts W (frag-linear) + rel;
// all other blocks stream node f32 -> bf16 (4 coalesced units/thread).
// do_node=0 launches with grid=1 (W+rel only, f32 fallback path).
// ---------------------------------------------------------------------------
__global__ __launch_bounds__(256) void cvt_k(
    const float* __restrict__ node, unsigned short* __restrict__ nodeb,
    const float* __restrict__ W, unsigned* __restrict__ Wbf,
    const float* __restrict__ rel, unsigned* __restrict__ relb,
    int do_node)
{
    const int t = threadIdx.x;
    if (blockIdx.x == gridDim.x - 1) {
        // ---- W + rel conversion ----
        #pragma unroll
        for (int i = 0; i < 8; ++i) {
            int u = t * 8 + i;          // 16B unit index, 0..2047
            int l = u & 63, f = u >> 6; // f = n*4 + ks
            int c16 = l & 15, q = l >> 4;
            int col = (f >> 2) * 16 + c16;
            int kb  = (f & 3) * 32 + q * 8;
            const float* wp = W + col * CDIM + kb;
            float4 w0 = *reinterpret_cast<const float4*>(wp);
            float4 w1 = *reinterpret_cast<const float4*>(wp + 4);
            uint4 pk;
            pk.x = (unsigned)f2bf(w0.x) | ((unsigned)f2bf(w0.y) << 16);
            pk.y = (unsigned)f2bf(w0.z) | ((unsigned)f2bf(w0.w) << 16);
            pk.z = (unsigned)f2bf(w1.x) | ((unsigned)f2bf(w1.y) << 16);
            pk.w = (unsigned)f2bf(w1.z) | ((unsigned)f2bf(w1.w) << 16);
            reinterpret_cast<uint4*>(Wbf)[u] = pk;
        }
        const float4* rs = reinterpret_cast<const float4*>(rel);
        uint4* rd = reinterpret_cast<uint4*>(relb);
        #pragma unroll
        for (int i = 0; i < 4; ++i) {
            int u = t * 4 + i;          // 0..1023
            float4 a = rs[u * 2], b2 = rs[u * 2 + 1];
            uint4 pk;
            pk.x = (unsigned)f2bf(a.x) | ((unsigned)f2bf(a.y) << 16);
            pk.y = (unsigned)f2bf(a.z) | ((unsigned)f2bf(a.w) << 16);
            pk.z = (unsigned)f2bf(b2.x) | ((unsigned)f2bf(b2.y) << 16);
            pk.w = (unsigned)f2bf(b2.z) | ((unsigned)f2bf(b2.w) << 16);
            rd[u] = pk;
        }
        return;
    }
    if (!do_node) return;
    const float4* src = reinterpret_cast<const float4*>(node);
    uint4* dst = reinterpret_cast<uint4*>(nodeb);
    #pragma unroll
    for (int i = 0; i < 4; ++i) {
        int v = blockIdx.x * 1024 + i * 256 + t;   // 8-float unit index
        if (v < NUNITS) {
            float4 a = src[v * 2], b2 = src[v * 2 + 1];
            uint4 pk;
            pk.x = (unsigned)f2bf(a.x) | ((unsigned)f2bf(a.y) << 16);
            pk.y = (unsigned)f2bf(a.z) | ((unsigned)f2bf(a.w) << 16);
            pk.z = (unsigned)f2bf(b2.x) | ((unsigned)f2bf(b2.y) << 16);
            pk.w = (unsigned)f2bf(b2.z) | ((unsigned)f2bf(b2.w) << 16);
            dst[v] = pk;
        }
    }
}

// ---------------------------------------------------------------------------
// edge_k: pure edge binning, 1 edge/thread, max TLP for the atomic chain.
// ---------------------------------------------------------------------------
__global__ __launch_bounds__(256) void edge_k(
    const int* __restrict__ eidx, unsigned* __restrict__ count,
    unsigned* __restrict__ payload)
{
    int e = blockIdx.x * 256 + threadIdx.x;
    if (e >= EE) return;
    int b = eidx[e];
    int t = eidx[EE + e];
    int s = eidx[2 * EE + e];
    int r = eidx[3 * EE + e];
    int seg = b * NN + t;
    unsigned slot = atomicAdd(count + seg, 1u);
    if (slot < CAP)
        payload[(size_t)seg * CAP + slot] = (unsigned)s | ((unsigned)r << 16);
}

// ---------------------------------------------------------------------------
// fused_k<NB>: unchanged (R16). 256 threads = 4 waves; block owns 16
// segments (16x128 tile). Quarter-per-segment gather, x4 branchless unroll,
// bf16 node rows; rel bf16 in LDS (272 B stride); Xl XOR-swizzled; MFMA
// per-wave 16 cols x2 from L2-hot Wbf.
// ---------------------------------------------------------------------------
template<bool NB>
__global__ __launch_bounds__(256) void fused_k(
    const void* __restrict__ nodev, const unsigned* __restrict__ relbg,
    const unsigned* __restrict__ count, const unsigned* __restrict__ payload,
    const unsigned* __restrict__ Wbf, float* __restrict__ out)
{
    __shared__ __align__(16) unsigned short Rl[64 * 136];   // 17408 B, 272B stride
    __shared__ __align__(16) unsigned short Xl[16 * CDIM];  // 4 KB swizzled

    const int tid = threadIdx.x;
    const int wav = tid >> 6;
    const int l   = tid & 63;
    const int q   = l >> 4;
    const int c   = l & 15;

    // stage relb (16 KB, L2-hot) into padded LDS: 1024 uint4, 4/thread
    {
        const uint4* src = reinterpret_cast<const uint4*>(relbg);
        #pragma unroll
        for (int i = 0; i < 4; ++i) {
            int u = i * 256 + tid;
            int row = u >> 4, cu = u & 15;
            *reinterpret_cast<uint4*>((char*)Rl + row * 272 + cu * 16) = src[u];
        }
    }

    const int seg = blockIdx.x * 16 + wav * 4 + q;
    const int b   = (seg >= NN) ? 1 : 0;
    unsigned cnt = count[seg];
    if (cnt > CAP) cnt = CAP;
    unsigned pv0 = payload[(size_t)seg * CAP + c];
    unsigned pv1 = payload[(size_t)seg * CAP + 16 + c];

    __syncthreads();  // Rl ready

    const char* rlb = (const char*)Rl + c * 16;

    float acc[8];
    #pragma unroll
    for (int i = 0; i < 8; ++i) acc[i] = 0.f;

    for (unsigned jb = 0; jb < cnt; jb += 4) {
        float w[4]; unsigned p[4];
        #pragma unroll
        for (int k = 0; k < 4; ++k) {
            unsigned j  = jb + k;
            unsigned jc = (j < cnt) ? j : (cnt - 1);
            w[k] = (j < cnt) ? 1.f : 0.f;
            p[k] = __shfl((jc & 16u) ? pv1 : pv0, (int)(jc & 15u), 16);
        }
        if constexpr (NB) {
            const unsigned short* nb =
                (const unsigned short*)nodev + (size_t)b * NN * CDIM + c * 8;
            bf16x8 hv[4]; bf16x8 rv[4];
            #pragma unroll
            for (int k = 0; k < 4; ++k) {
                int s = (int)(p[k] & 0xFFFFu);
                int r = (int)((p[k] >> 16) & 63u);
                hv[k] = *reinterpret_cast<const bf16x8*>(nb + (size_t)s * CDIM);
                rv[k] = *reinterpret_cast<const bf16x8*>(rlb + r * 272);
            }
            #pragma unroll
            for (int k = 0; k < 4; ++k)
                #pragma unroll
                for (int i = 0; i < 8; ++i)
                    acc[i] = fmaf(w[k],
                        bf2f((unsigned short)hv[k][i]) - bf2f((unsigned short)rv[k][i]),
                        acc[i]);
        } else {
            const float* nb = (const float*)nodev + (size_t)b * NN * CDIM + c * 8;
            float4 ha[4], hb[4]; bf16x8 rv[4];
            #pragma unroll
            for (int k = 0; k < 4; ++k) {
                int s = (int)(p[k] & 0xFFFFu);
                int r = (int)((p[k] >> 16) & 63u);
                const float* h = nb + (size_t)s * CDIM;
                ha[k] = *reinterpret_cast<const float4*>(h);
                hb[k] = *reinterpret_cast<const float4*>(h + 4);
                rv[k] = *reinterpret_cast<const bf16x8*>(rlb + r * 272);
            }
            #pragma unroll
            for (int k = 0; k < 4; ++k) {
                acc[0] = fmaf(w[k], ha[k].x - bf2f((unsigned short)rv[k][0]), acc[0]);
                acc[1] = fmaf(w[k], ha[k].y - bf2f((unsigned short)rv[k][1]), acc[1]);
                acc[2] = fmaf(w[k], ha[k].z - bf2f((unsigned short)rv[k][2]), acc[2]);
                acc[3] = fmaf(w[k], ha[k].w - bf2f((unsigned short)rv[k][3]), acc[3]);
                acc[4] = fmaf(w[k], hb[k].x - bf2f((unsigned short)rv[k][4]), acc[4]);
                acc[5] = fmaf(w[k], hb[k].y - bf2f((unsigned short)rv[k][5]), acc[5]);
                acc[6] = fmaf(w[k], hb[k].z - bf2f((unsigned short)rv[k][6]), acc[6]);
                acc[7] = fmaf(w[k], hb[k].w - bf2f((unsigned short)rv[k][7]), acc[7]);
            }
        }
    }

    // mean + bf16 pack; lane c writes its own 16 B of row (wav*4 + q)
    {
        float inv = 1.f / (float)cnt;  // cnt >= 1 (cover edges)
        int row = wav * 4 + q;
        uint4 pk;
        pk.x = (unsigned)f2bf(acc[0] * inv) | ((unsigned)f2bf(acc[1] * inv) << 16);
        pk.y = (unsigned)f2bf(acc[2] * inv) | ((unsigned)f2bf(acc[3] * inv) << 16);
        pk.z = (unsigned)f2bf(acc[4] * inv) | ((unsigned)f2bf(acc[5] * inv) << 16);
        pk.w = (unsigned)f2bf(acc[6] * inv) | ((unsigned)f2bf(acc[7] * inv) << 16);
        int off = (row * 256 + c * 16) ^ ((row & 7) << 4);
        *reinterpret_cast<uint4*>((char*)Xl + off) = pk;
    }

    __syncthreads();  // x-tile staged

    // A-frags: lane row = c, k = ks*32 + q*8 + j
    bf16x8 afr[4];
    #pragma unroll
    for (int ks = 0; ks < 4; ++ks) {
        int off = (c * 256 + ks * 64 + q * 16) ^ ((c & 7) << 4);
        afr[ks] = *reinterpret_cast<const bf16x8*>((const char*)Xl + off);
    }

    // wave computes cols wav*32 .. wav*32+31 (n = wav*2, wav*2+1)
    size_t rowbase = (size_t)blockIdx.x * 16;
    #pragma unroll
    for (int n2 = 0; n2 < 2; ++n2) {
        int n = wav * 2 + n2;
        f32x4 accv = (f32x4){0.f, 0.f, 0.f, 0.f};
        #pragma unroll
        for (int ks = 0; ks < 4; ++ks) {
            bf16x8 bfr = reinterpret_cast<const bf16x8*>(Wbf)[(n * 4 + ks) * 64 + l];
            accv = __builtin_amdgcn_mfma_f32_16x16x32_bf16(afr[ks], bfr, accv, 0, 0, 0);
        }
        #pragma unroll
        for (int j = 0; j < 4; ++j)
            out[(rowbase + q * 4 + j) * CDIM + n * 16 + c] = accv[j];
    }
}

extern "C" void kernel_launch(void* const* d_in, const int* in_sizes, int n_in,
                              void* d_out, int out_size, void* d_ws, size_t ws_size,
                              hipStream_t stream) {
    const float* node = (const float*)d_in[0];
    const int*   eidx = (const int*)d_in[1];
    const float* rel  = (const float*)d_in[2];
    const float* W    = (const float*)d_in[3];
    float* out = (float*)d_out;

    // ws: count u32[SEGS] @0 (400000); payload u32[SEGS*CAP] @400000
    //     (ends 13200000); Wbf 32 KB @13200000; relb 16 KB @13232768;
    //     nodeb bf16[SEGS*CDIM] @13249152 (ends 38849152)
    unsigned* count   = (unsigned*)d_ws;
    unsigned* payload = (unsigned*)((char*)d_ws + 400000);
    unsigned* Wbf     = (unsigned*)((char*)d_ws + 13200000);
    unsigned* relb    = (unsigned*)((char*)d_ws + 13232768);
    unsigned short* nodeb = (unsigned short*)((char*)d_ws + 13249152);
    const size_t NEED = 13249152ull + (size_t)SEGS * CDIM * 2;
    const bool use_bf = (ws_size >= NEED);

    hipMemsetAsync(count, 0, (size_t)SEGS * sizeof(unsigned), stream);

    cvt_k<<<use_bf ? (CVB + 1) : 1, 256, 0, stream>>>(node, nodeb, W, Wbf,
                                                      rel, relb, use_bf ? 1 : 0);
    edge_k<<<EBLK, 256, 0, stream>>>(eidx, count, payload);

    if (use_bf)
        fused_k<true><<<SEGS / 16, 256, 0, stream>>>(nodeb, relb, count, payload, Wbf, out);
    else
        fused_k<false><<<SEGS / 16, 256, 0, stream>>>(node, relb, count, payload, Wbf, out);
}

// Round 26
// 73.564 us; speedup vs baseline: 1.1924x; 1.1924x over previous
//
#include <hip/hip_runtime.h>

constexpr int BB   = 2;
constexpr int NN   = 50000;
constexpr int EE   = 600000;
constexpr int CDIM = 128;
constexpr int SEGS = BB * NN;   // 100000
constexpr int CAP  = 32;        // max degree = 1 + Poisson(5); P(>=32) ~ 1e-10
constexpr int NUNITS = SEGS * CDIM / 8;            // 1.6M 8-float units
constexpr int EB4  = (EE + 1023) / 1024;           // 586 edge blocks (4 edges/thr)
constexpr int CV12 = (NUNITS + 3071) / 3072;       // 521 cvt blocks (12 units/thr)

typedef __attribute__((ext_vector_type(8))) short bf16x8;
typedef __attribute__((ext_vector_type(4))) float f32x4;

__device__ __forceinline__ unsigned short f2bf(float f) {
    unsigned u = __builtin_bit_cast(unsigned, f);
    return (unsigned short)((u + 0x7FFFu + ((u >> 16) & 1u)) >> 16);  // RNE
}
__device__ __forceinline__ float bf2f(unsigned short v) {
    unsigned u = ((unsigned)v) << 16;
    return __builtin_bit_cast(float, u);
}

// ---------------------------------------------------------------------------
// binscatter_k — R16 structure (best validated: 73.4 / 73.7 µs).
// 1:1 interleave (even block = edge role, odd = cvt role) inside ONE kernel
// so the latency-bound edge role and BW-bound cvt role are co-resident
// (R25 proved splitting them costs +14 µs).
//   edge role: 4 edges/thread, independent atomic chains.
//   cvt role: 12 coalesced units/thread, node f32 -> bf16.
//   Last even block (eid==EB4): W + rel conversion.
// ---------------------------------------------------------------------------
__global__ __launch_bounds__(256) void binscatter_k(
    const int* __restrict__ eidx, unsigned* __restrict__ count,
    unsigned* __restrict__ payload, const float* __restrict__ W,
    unsigned* __restrict__ Wbf, const float* __restrict__ rel,
    unsigned* __restrict__ relb, const float* __restrict__ node,
    unsigned short* __restrict__ nodeb, int do_cvt)
{
    const int t = threadIdx.x;

    if (blockIdx.x & 1) {
        // ---- node conversion role: 12 independent coalesced streams ----
        if (!do_cvt) return;
        int cid = blockIdx.x >> 1;
        if (cid >= CV12) return;
        const float4* src = reinterpret_cast<const float4*>(node);
        uint4* dst = reinterpret_cast<uint4*>(nodeb);
        #pragma unroll
        for (int i = 0; i < 12; ++i) {
            int v = cid * 3072 + i * 256 + t;   // 8-float unit index
            if (v < NUNITS) {
                float4 a = src[v * 2], b2 = src[v * 2 + 1];
                uint4 pk;
                pk.x = (unsigned)f2bf(a.x) | ((unsigned)f2bf(a.y) << 16);
                pk.y = (unsigned)f2bf(a.z) | ((unsigned)f2bf(a.w) << 16);
                pk.z = (unsigned)f2bf(b2.x) | ((unsigned)f2bf(b2.y) << 16);
                pk.w = (unsigned)f2bf(b2.z) | ((unsigned)f2bf(b2.w) << 16);
                dst[v] = pk;
            }
        }
        return;
    }

    int eid = blockIdx.x >> 1;
    if (eid == EB4) {
        // ---- W + rel conversion role ----
        #pragma unroll
        for (int i = 0; i < 8; ++i) {
            int u = t * 8 + i;          // 16B unit index, 0..2047
            int l = u & 63, f = u >> 6; // f = n*4 + ks
            int c16 = l & 15, q = l >> 4;
            int col = (f >> 2) * 16 + c16;
            int kb  = (f & 3) * 32 + q * 8;
            const float* wp = W + col * CDIM + kb;
            float4 w0 = *reinterpret_cast<const float4*>(wp);
            float4 w1 = *reinterpret_cast<const float4*>(wp + 4);
            uint4 pk;
            pk.x = (unsigned)f2bf(w0.x) | ((unsigned)f2bf(w0.y) << 16);
            pk.y = (unsigned)f2bf(w0.z) | ((unsigned)f2bf(w0.w) << 16);
            pk.z = (unsigned)f2bf(w1.x) | ((unsigned)f2bf(w1.y) << 16);
            pk.w = (unsigned)f2bf(w1.z) | ((unsigned)f2bf(w1.w) << 16);
            reinterpret_cast<uint4*>(Wbf)[u] = pk;
        }
        const float4* rs = reinterpret_cast<const float4*>(rel);
        uint4* rd = reinterpret_cast<uint4*>(relb);
        #pragma unroll
        for (int i = 0; i < 4; ++i) {
            int u = t * 4 + i;          // 0..1023
            float4 a = rs[u * 2], b2 = rs[u * 2 + 1];
            uint4 pk;
            pk.x = (unsigned)f2bf(a.x) | ((unsigned)f2bf(a.y) << 16);
            pk.y = (unsigned)f2bf(a.z) | ((unsigned)f2bf(a.w) << 16);
            pk.z = (unsigned)f2bf(b2.x) | ((unsigned)f2bf(b2.y) << 16);
            pk.w = (unsigned)f2bf(b2.z) | ((unsigned)f2bf(b2.w) << 16);
            rd[u] = pk;
        }
        return;
    }

    // ---- edge-binning role: 4 edges/thread, independent chains ----
    int bb[4], tt[4], ss[4], rr[4]; bool ok[4];
    #pragma unroll
    for (int i = 0; i < 4; ++i) {
        int e  = eid * 1024 + i * 256 + t;
        ok[i]  = (e < EE);
        int ec = ok[i] ? e : (EE - 1);
        bb[i] = eidx[ec];
        tt[i] = eidx[EE + ec];
        ss[i] = eidx[2 * EE + ec];
        rr[i] = eidx[3 * EE + ec];
    }
    #pragma unroll
    for (int i = 0; i < 4; ++i) {
        if (ok[i]) {
            int seg = bb[i] * NN + tt[i];
            unsigned slot = atomicAdd(count + seg, 1u);
            if (slot < CAP)
                payload[(size_t)seg * CAP + slot] =
                    (unsigned)ss[i] | ((unsigned)rr[i] << 16);
        }
    }
}

// ---------------------------------------------------------------------------
// fused_k<NB>: 256 threads = 4 waves; block owns 16 segments (16x128 tile).
// Gather: each 16-lane QUARTER owns one segment (lane c holds dims
// c*8..c*8+7). j-loop unrolled x4 branchless (clamped idx + 0/1 weight).
// NB=true: node rows bf16 (256 B, L3-resident nodeb). rel bf16 in LDS,
// 272 B padded stride. x-row -> Xl bf16 XOR-swizzled; mean fused.
// MFMA: wave w loads 8 B-frags from L2-hot Wbf, computes cols w*32..+31.
// ---------------------------------------------------------------------------
template<bool NB>
__global__ __launch_bounds__(256) void fused_k(
    const void* __restrict__ nodev, const unsigned* __restrict__ relbg,
    const unsigned* __restrict__ count, const unsigned* __restrict__ payload,
    const unsigned* __restrict__ Wbf, float* __restrict__ out)
{
    __shared__ __align__(16) unsigned short Rl[64 * 136];   // 17408 B, 272B stride
    __shared__ __align__(16) unsigned short Xl[16 * CDIM];  // 4 KB swizzled

    const int tid = threadIdx.x;
    const int wav = tid >> 6;
    const int l   = tid & 63;
    const int q   = l >> 4;
    const int c   = l & 15;

    // stage relb (16 KB, L2-hot) into padded LDS: 1024 uint4, 4/thread
    {
        const uint4* src = reinterpret_cast<const uint4*>(relbg);
        #pragma unroll
        for (int i = 0; i < 4; ++i) {
            int u = i * 256 + tid;
            int row = u >> 4, cu = u & 15;
            *reinterpret_cast<uint4*>((char*)Rl + row * 272 + cu * 16) = src[u];
        }
    }

    const int seg = blockIdx.x * 16 + wav * 4 + q;
    const int b   = (seg >= NN) ? 1 : 0;
    unsigned cnt = count[seg];
    if (cnt > CAP) cnt = CAP;
    unsigned pv0 = payload[(size_t)seg * CAP + c];
    unsigned pv1 = payload[(size_t)seg * CAP + 16 + c];

    __syncthreads();  // Rl ready

    const char* rlb = (const char*)Rl + c * 16;

    float acc[8];
    #pragma unroll
    for (int i = 0; i < 8; ++i) acc[i] = 0.f;

    for (unsigned jb = 0; jb < cnt; jb += 4) {
        float w[4]; unsigned p[4];
        #pragma unroll
        for (int k = 0; k < 4; ++k) {
            unsigned j  = jb + k;
            unsigned jc = (j < cnt) ? j : (cnt - 1);
            w[k] = (j < cnt) ? 1.f : 0.f;
            p[k] = __shfl((jc & 16u) ? pv1 : pv0, (int)(jc & 15u), 16);
        }
        if constexpr (NB) {
            const unsigned short* nb =
                (const unsigned short*)nodev + (size_t)b * NN * CDIM + c * 8;
            bf16x8 hv[4]; bf16x8 rv[4];
            #pragma unroll
            for (int k = 0; k < 4; ++k) {
                int s = (int)(p[k] & 0xFFFFu);
                int r = (int)((p[k] >> 16) & 63u);
                hv[k] = *reinterpret_cast<const bf16x8*>(nb + (size_t)s * CDIM);
                rv[k] = *reinterpret_cast<const bf16x8*>(rlb + r * 272);
            }
            #pragma unroll
            for (int k = 0; k < 4; ++k)
                #pragma unroll
                for (int i = 0; i < 8; ++i)
                    acc[i] = fmaf(w[k],
                        bf2f((unsigned short)hv[k][i]) - bf2f((unsigned short)rv[k][i]),
                        acc[i]);
        } else {
            const float* nb = (const float*)nodev + (size_t)b * NN * CDIM + c * 8;
            float4 ha[4], hb[4]; bf16x8 rv[4];
            #pragma unroll
            for (int k = 0; k < 4; ++k) {
                int s = (int)(p[k] & 0xFFFFu);
                int r = (int)((p[k] >> 16) & 63u);
                const float* h = nb + (size_t)s * CDIM;
                ha[k] = *reinterpret_cast<const float4*>(h);
                hb[k] = *reinterpret_cast<const float4*>(h + 4);
                rv[k] = *reinterpret_cast<const bf16x8*>(rlb + r * 272);
            }
            #pragma unroll
            for (int k = 0; k < 4; ++k) {
                acc[0] = fmaf(w[k], ha[k].x - bf2f((unsigned short)rv[k][0]), acc[0]);
                acc[1] = fmaf(w[k], ha[k].y - bf2f((unsigned short)rv[k][1]), acc[1]);
                acc[2] = fmaf(w[k], ha[k].z - bf2f((unsigned short)rv[k][2]), acc[2]);
                acc[3] = fmaf(w[k], ha[k].w - bf2f((unsigned short)rv[k][3]), acc[3]);
                acc[4] = fmaf(w[k], hb[k].x - bf2f((unsigned short)rv[k][4]), acc[4]);
                acc[5] = fmaf(w[k], hb[k].y - bf2f((unsigned short)rv[k][5]), acc[5]);
                acc[6] = fmaf(w[k], hb[k].z - bf2f((unsigned short)rv[k][6]), acc[6]);
                acc[7] = fmaf(w[k], hb[k].w - bf2f((unsigned short)rv[k][7]), acc[7]);
            }
        }
    }

    // mean + bf16 pack; lane c writes its own 16 B of row (wav*4 + q)
    {
        float inv = 1.f / (float)cnt;  // cnt >= 1 (cover edges)
        int row = wav * 4 + q;
        uint4 pk;
        pk.x = (unsigned)f2bf(acc[0] * inv) | ((unsigned)f2bf(acc[1] * inv) << 16);
        pk.y = (unsigned)f2bf(acc[2] * inv) | ((unsigned)f2bf(acc[3] * inv) << 16);
        pk.z = (unsigned)f2bf(acc[4] * inv) | ((unsigned)f2bf(acc[5] * inv) << 16);
        pk.w = (unsigned)f2bf(acc[6] * inv) | ((unsigned)f2bf(acc[7] * inv) << 16);
        int off = (row * 256 + c * 16) ^ ((row & 7) << 4);
        *reinterpret_cast<uint4*>((char*)Xl + off) = pk;
    }

    __syncthreads();  // x-tile staged

    // A-frags: lane row = c, k = ks*32 + q*8 + j
    bf16x8 afr[4];
    #pragma unroll
    for (int ks = 0; ks < 4; ++ks) {
        int off = (c * 256 + ks * 64 + q * 16) ^ ((c & 7) << 4);
        afr[ks] = *reinterpret_cast<const bf16x8*>((const char*)Xl + off);
    }

    // wave computes cols wav*32 .. wav*32+31 (n = wav*2, wav*2+1)
    size_t rowbase = (size_t)blockIdx.x * 16;
    #pragma unroll
    for (int n2 = 0; n2 < 2; ++n2) {
        int n = wav * 2 + n2;
        f32x4 accv = (f32x4){0.f, 0.f, 0.f, 0.f};
        #pragma unroll
        for (int ks = 0; ks < 4; ++ks) {
            bf16x8 bfr = reinterpret_cast<const bf16x8*>(Wbf)[(n * 4 + ks) * 64 + l];
            accv = __builtin_amdgcn_mfma_f32_16x16x32_bf16(afr[ks], bfr, accv, 0, 0, 0);
        }
        #pragma unroll
        for (int j = 0; j < 4; ++j)
            out[(rowbase + q * 4 + j) * CDIM + n * 16 + c] = accv[j];
    }
}

extern "C" void kernel_launch(void* const* d_in, const int* in_sizes, int n_in,
                              void* d_out, int out_size, void* d_ws, size_t ws_size,
                              hipStream_t stream) {
    const float* node = (const float*)d_in[0];
    const int*   eidx = (const int*)d_in[1];
    const float* rel  = (const float*)d_in[2];
    const float* W    = (const float*)d_in[3];
    float* out = (float*)d_out;

    // ws: count u32[SEGS] @0 (400000); payload u32[SEGS*CAP] @400000
    //     (ends 13200000); Wbf 32 KB @13200000; relb 16 KB @13232768;
    //     nodeb bf16[SEGS*CDIM] @13249152 (ends 38849152)
    unsigned* count   = (unsigned*)d_ws;
    unsigned* payload = (unsigned*)((char*)d_ws + 400000);
    unsigned* Wbf     = (unsigned*)((char*)d_ws + 13200000);
    unsigned* relb    = (unsigned*)((char*)d_ws + 13232768);
    unsigned short* nodeb = (unsigned short*)((char*)d_ws + 13249152);
    const size_t NEED = 13249152ull + (size_t)SEGS * CDIM * 2;
    const bool use_bf = (ws_size >= NEED);

    hipMemsetAsync(count, 0, (size_t)SEGS * sizeof(unsigned), stream);

    binscatter_k<<<2 * (EB4 + 1), 256, 0, stream>>>(eidx, count, payload, W, Wbf,
                                                    rel, relb, node, nodeb,
                                                    use_bf ? 1 : 0);

    if (use_bf)
        fused_k<true><<<SEGS / 16, 256, 0, stream>>>(nodeb, relb, count, payload, Wbf, out);
    else
        fused_k<false><<<SEGS / 16, 256, 0, stream>>>(node, relb, count, payload, Wbf, out);
}